// Round 3
// baseline (251.166 us; speedup 1.0000x reference)
//
#include <hip/hip_runtime.h>
#include <math.h>

#define BATCH 131072
#define DIM 256
#define NK 5
#define BT 3.0f
#define NBLK 1280   // 5 blocks/CU x 256 CU, fully co-resident persistent grid

// wave64 sum via DPP (VALU pipe, no LDS). Result valid in lane 63.
__device__ __forceinline__ float wave_sum_dpp(float x) {
    x += __int_as_float(__builtin_amdgcn_update_dpp(0, __float_as_int(x), 0x111, 0xF, 0xF, true)); // row_shr:1
    x += __int_as_float(__builtin_amdgcn_update_dpp(0, __float_as_int(x), 0x112, 0xF, 0xF, true)); // row_shr:2
    x += __int_as_float(__builtin_amdgcn_update_dpp(0, __float_as_int(x), 0x114, 0xF, 0xF, true)); // row_shr:4
    x += __int_as_float(__builtin_amdgcn_update_dpp(0, __float_as_int(x), 0x118, 0xF, 0xF, true)); // row_shr:8
    x += __int_as_float(__builtin_amdgcn_update_dpp(0, __float_as_int(x), 0x142, 0xA, 0xF, true)); // row_bcast:15 -> rows 1,3
    x += __int_as_float(__builtin_amdgcn_update_dpp(0, __float_as_int(x), 0x143, 0xC, 0xF, true)); // row_bcast:31 -> rows 2,3
    return x;
}

__global__ __launch_bounds__(256, 5) void rqs_kernel(
    const float* __restrict__ u,
    const float* __restrict__ wp,
    const float* __restrict__ hp,
    const float* __restrict__ dp,
    float* __restrict__ x_out,
    float* __restrict__ ld_out)
{
    // tabA[k*DIM + dim] = (xk, 1/width, yk, height); tabB = (deriv[k], deriv[k+1])
    __shared__ float4 tabA[NK * DIM];
    __shared__ float2 tabB[NK * DIM];
    const int tid = threadIdx.x;

    // ---------- per-dim table precompute: thread t handles dim t ----------
    {
        const int dm = tid;
        float v[NK];
        float mx, sum, scale, c;
        float wid[NK], xpos[NK], hei[NK], ypos[NK], dv[NK + 1];

        mx = -1e30f;
        #pragma unroll
        for (int k = 0; k < NK; k++) { v[k] = wp[dm * NK + k]; mx = fmaxf(mx, v[k]); }
        sum = 0.f;
        #pragma unroll
        for (int k = 0; k < NK; k++) { v[k] = expf(v[k] - mx); sum += v[k]; }
        scale = 6.0f / sum;
        c = -BT;
        #pragma unroll
        for (int k = 0; k < NK; k++) { wid[k] = v[k] * scale; xpos[k] = c; c += wid[k]; }

        mx = -1e30f;
        #pragma unroll
        for (int k = 0; k < NK; k++) { v[k] = hp[dm * NK + k]; mx = fmaxf(mx, v[k]); }
        sum = 0.f;
        #pragma unroll
        for (int k = 0; k < NK; k++) { v[k] = expf(v[k] - mx); sum += v[k]; }
        scale = 6.0f / sum;
        c = -BT;
        #pragma unroll
        for (int k = 0; k < NK; k++) { hei[k] = v[k] * scale; ypos[k] = c; c += hei[k]; }

        dv[0] = 1.0f; dv[NK] = 1.0f;
        #pragma unroll
        for (int k = 0; k < 4; k++) dv[1 + k] = log1pf(expf(dp[dm * 4 + k]));

        #pragma unroll
        for (int k = 0; k < NK; k++) {
            tabA[k * DIM + dm] = make_float4(xpos[k], 1.0f / wid[k], ypos[k], hei[k]);
            tabB[k * DIM + dm] = make_float2(dv[k], dv[k + 1]);
        }
    }
    __syncthreads();

    const int lane = tid & 63;
    const int wv   = tid >> 6;

    // thread owns dims lane, lane+64, lane+128, lane+192
    float kn[4][4];
    #pragma unroll
    for (int j = 0; j < 4; j++) {
        #pragma unroll
        for (int i = 0; i < 4; i++)
            kn[j][i] = tabA[(i + 1) * DIM + lane + 64 * j].x;
    }

    const int gw = (blockIdx.x << 2) | wv;        // global wave id, 0..5119
    const int stride = NBLK * 4 * 4;              // rows consumed per iteration by all waves

    float cur[4][4];
    int row = gw * 4;
    #pragma unroll
    for (int rr = 0; rr < 4; rr++) {
        const float* up = u + (size_t)(row + rr) * DIM + lane;
        #pragma unroll
        for (int j = 0; j < 4; j++) cur[rr][j] = up[64 * j];
    }

    for (; row < BATCH; row += stride) {
        // ---- prefetch next iteration's u (wave-uniform guard) ----
        const int nrow = row + stride;
        float nxt[4][4];
        if (nrow < BATCH) {
            #pragma unroll
            for (int rr = 0; rr < 4; rr++) {
                const float* up = u + (size_t)(nrow + rr) * DIM + lane;
                #pragma unroll
                for (int j = 0; j < 4; j++) nxt[rr][j] = up[64 * j];
            }
        }

        #pragma unroll
        for (int rr = 0; rr < 4; rr++) {
            float xo[4];
            float ldsum = 0.f;
            #pragma unroll
            for (int j = 0; j < 4; j++) {
                float uval = cur[rr][j];
                float uc = fminf(fmaxf(uval, -BT), BT);
                bool inside = (uval >= -BT) && (uval <= BT);
                int idx = 0;
                idx += (uc >= kn[j][0]);
                idx += (uc >= kn[j][1]);
                idx += (uc >= kn[j][2]);
                idx += (uc >= kn[j][3]);
                const int a = idx * DIM + lane + 64 * j;
                float4 A  = tabA[a];
                float2 Bv = tabB[a];
                float xk = A.x, iw = A.y, yk = A.z, hk = A.w;
                float dk = Bv.x, dk1 = Bv.y;

                float delta = hk * iw;
                float theta = (uc - xk) * iw;
                float omt   = 1.0f - theta;
                float t1m   = theta * omt;
                float th2   = theta * theta;
                float denom = delta + (dk + dk1 - 2.0f * delta) * t1m;
                float inv_d = __fdividef(1.0f, denom);
                float num   = hk * (delta * th2 + dk * t1m);
                float x_in  = yk + num * inv_d;
                float ldn   = (delta * delta) *
                              (dk1 * th2 + 2.0f * delta * t1m + dk * omt * omt);
                float ld    = __logf(ldn * inv_d * inv_d);

                xo[j] = inside ? x_in : uval;
                ldsum += inside ? ld : 0.0f;
            }
            float* xp = x_out + (size_t)(row + rr) * DIM + lane;
            #pragma unroll
            for (int j = 0; j < 4; j++)
                __builtin_nontemporal_store(xo[j], xp + 64 * j);

            float tot = wave_sum_dpp(ldsum);           // valid in lane 63
            if (lane == 63)
                __builtin_nontemporal_store(tot, ld_out + row + rr);
        }

        if (nrow < BATCH) {
            #pragma unroll
            for (int rr = 0; rr < 4; rr++)
                #pragma unroll
                for (int j = 0; j < 4; j++) cur[rr][j] = nxt[rr][j];
        }
    }
}

extern "C" void kernel_launch(void* const* d_in, const int* in_sizes, int n_in,
                              void* d_out, int out_size, void* d_ws, size_t ws_size,
                              hipStream_t stream) {
    const float* u  = (const float*)d_in[0];
    const float* w  = (const float*)d_in[1];
    const float* h  = (const float*)d_in[2];
    const float* dd = (const float*)d_in[3];
    float* x  = (float*)d_out;
    float* ld = x + (size_t)BATCH * DIM;
    rqs_kernel<<<NBLK, 256, 0, stream>>>(u, w, h, dd, x, ld);
}

// Round 4
// 245.856 us; speedup vs baseline: 1.0216x; 1.0216x over previous
//
#include <hip/hip_runtime.h>
#include <math.h>

#define BATCH 131072
#define DIM 256
#define NK 5
#define BT 3.0f
#define NBLK 1024    // 4 blocks/CU x 256 CU, exactly co-resident
#define NTHR 512     // 8 waves/block -> 32 waves/CU = 100% occupancy
#define ITERS 8      // BATCH / (NBLK * 8 waves * 2 rows)

__global__ __launch_bounds__(NTHR, 8) void rqs_kernel(
    const float* __restrict__ u,
    const float* __restrict__ wp,
    const float* __restrict__ hp,
    const float* __restrict__ dp,
    float* __restrict__ x_out,
    float* __restrict__ ld_out)
{
    // Interleaved per-(bin,dim) record, 32 B:
    //   tab[2*(k*DIM+dim)]   = (xk, 1/width, s = dk+dk1-2*delta, delta)
    //   tab[2*(k*DIM+dim)+1] = (p = h*(delta-dk), q = h*dk, yk, rb = 2*(delta-dk))
    // Math:  theta = (uc-xk)*iw
    //        denom = fma(fma(-s,th,s),th,delta)            (= delta + s*th*(1-th))
    //        num   = th*fma(p,th,q)                        (= h*(delta*th^2 + dk*th(1-th)))
    //        ldq   = fma(fma(s,th,rb),th,dk)               (= dk1*th^2+2delta*th(1-th)+dk*(1-th)^2)
    //        ld    = log(ldq * delta^2 * invd^2)
    // At th==0 (low tail, dk=1) and th==1 (high tail, dk1=1) ldq*d2*invd^2 == 1 -> ld == 0,
    // so no 'inside' select needed on ld.
    __shared__ float4 tab[NK * DIM * 2];   // 40960 B; 4 blocks = exactly 160 KiB/CU
    const int tid = threadIdx.x;

    if (tid < DIM) {
        const int dm = tid;
        float v[NK], wid[NK], xpos[NK], hei[NK], ypos[NK], dv[NK + 1];
        float mx, sum, scale, c;

        mx = -1e30f;
        #pragma unroll
        for (int k = 0; k < NK; k++) { v[k] = wp[dm * NK + k]; mx = fmaxf(mx, v[k]); }
        sum = 0.f;
        #pragma unroll
        for (int k = 0; k < NK; k++) { v[k] = expf(v[k] - mx); sum += v[k]; }
        scale = 6.0f / sum;
        c = -BT;
        #pragma unroll
        for (int k = 0; k < NK; k++) { wid[k] = v[k] * scale; xpos[k] = c; c += wid[k]; }

        mx = -1e30f;
        #pragma unroll
        for (int k = 0; k < NK; k++) { v[k] = hp[dm * NK + k]; mx = fmaxf(mx, v[k]); }
        sum = 0.f;
        #pragma unroll
        for (int k = 0; k < NK; k++) { v[k] = expf(v[k] - mx); sum += v[k]; }
        scale = 6.0f / sum;
        c = -BT;
        #pragma unroll
        for (int k = 0; k < NK; k++) { hei[k] = v[k] * scale; ypos[k] = c; c += hei[k]; }

        dv[0] = 1.0f; dv[NK] = 1.0f;
        #pragma unroll
        for (int k = 0; k < 4; k++) dv[1 + k] = log1pf(expf(dp[dm * 4 + k]));

        #pragma unroll
        for (int k = 0; k < NK; k++) {
            float iw  = 1.0f / wid[k];
            float dlt = hei[k] * iw;
            float dk  = dv[k], dk1 = dv[k + 1];
            tab[2 * (k * DIM + dm)]     = make_float4(xpos[k], iw, dk + dk1 - 2.0f * dlt, dlt);
            tab[2 * (k * DIM + dm) + 1] = make_float4(hei[k] * (dlt - dk), hei[k] * dk,
                                                      ypos[k], 2.0f * (dlt - dk));
        }
    }
    __syncthreads();

    const int lane = tid & 63;
    const int wv   = tid >> 6;

    // thread owns dims lane, lane+64, lane+128, lane+192; preload interior x-knots
    float kn[4][4];
    #pragma unroll
    for (int j = 0; j < 4; j++)
        #pragma unroll
        for (int i = 0; i < 4; i++)
            kn[j][i] = tab[2 * ((i + 1) * DIM + lane + 64 * j)].x;

    const int g = (blockIdx.x << 3) | wv;   // global wave id, 0..8191

    for (int it = 0; it < ITERS; it++) {
        const int r0 = (it << 14) | (g << 1);   // 16384 contiguous rows per sweep
        const float* up = u + (size_t)r0 * DIM + lane;

        float uin[2][4];
        #pragma unroll
        for (int rr = 0; rr < 2; rr++)
            #pragma unroll
            for (int j = 0; j < 4; j++)
                uin[rr][j] = up[rr * DIM + 64 * j];

        float lds[2] = {0.f, 0.f};
        #pragma unroll
        for (int rr = 0; rr < 2; rr++) {
            float xo[4];
            #pragma unroll
            for (int j = 0; j < 4; j++) {
                float uval = uin[rr][j];
                float uc = fminf(fmaxf(uval, -BT), BT);
                int idx = 0;
                idx += (uc >= kn[j][0]);
                idx += (uc >= kn[j][1]);
                idx += (uc >= kn[j][2]);
                idx += (uc >= kn[j][3]);
                const int a = 2 * (idx * DIM + lane + 64 * j);
                float4 A  = tab[a];
                float4 Bv = tab[a + 1];
                float xk = A.x, iw = A.y, s = A.z, dlt = A.w;
                float p = Bv.x, q = Bv.y, yk = Bv.z, rb = Bv.w;

                float th    = (uc - xk) * iw;
                float dk    = fmaf(-0.5f, rb, dlt);
                float r2    = dlt * dlt;
                float denom = fmaf(fmaf(-s, th, s), th, dlt);
                float invd  = __builtin_amdgcn_rcpf(denom);
                float num   = th * fmaf(p, th, q);
                float x_in  = fmaf(num, invd, yk);
                float ldq   = fmaf(fmaf(s, th, rb), th, dk);
                float ld    = __logf(ldq * r2 * invd * invd);

                xo[j] = (uc == uval) ? x_in : uval;
                lds[rr] += ld;           // == 0 (to fp eps) for tail elements
            }
            float* xp = x_out + (size_t)(r0 + rr) * DIM + lane;
            #pragma unroll
            for (int j = 0; j < 4; j++)
                __builtin_nontemporal_store(xo[j], xp + 64 * j);
        }

        #pragma unroll
        for (int off = 32; off > 0; off >>= 1) {
            lds[0] += __shfl_down(lds[0], off, 64);
            lds[1] += __shfl_down(lds[1], off, 64);
        }
        if (lane == 0) {
            __builtin_nontemporal_store(lds[0], ld_out + r0);
            __builtin_nontemporal_store(lds[1], ld_out + r0 + 1);
        }
    }
}

extern "C" void kernel_launch(void* const* d_in, const int* in_sizes, int n_in,
                              void* d_out, int out_size, void* d_ws, size_t ws_size,
                              hipStream_t stream) {
    const float* u  = (const float*)d_in[0];
    const float* w  = (const float*)d_in[1];
    const float* h  = (const float*)d_in[2];
    const float* dd = (const float*)d_in[3];
    float* x  = (float*)d_out;
    float* ld = x + (size_t)BATCH * DIM;
    rqs_kernel<<<NBLK, NTHR, 0, stream>>>(u, w, h, dd, x, ld);
}